// Round 1
// baseline (2013.896 us; speedup 1.0000x reference)
//
#include <hip/hip_runtime.h>
#include <math.h>

// ---------------- problem constants (fixed inputs: key 0) ----------------
// mu: [16384,1024] fp32, labels: [16384] int32 in [0,10)
#define BN 16384
#define DN 1024
#define PN 64      // subspace block size
#define CHEB_D 20  // Chebyshev degree per stage

// ---------------- workspace layout (bytes, all 256-aligned) ----------------
static constexpr size_t OFF_C    = 0x000000;  // f32 [1024*1024]  (G then C)   [ZERO]
static constexpr size_t OFF_P    = 0x400000;  // f32 [16][64][1024] mv partials
static constexpr size_t OFF_Y0   = 0x800000;  // f32 [64][1024]
static constexpr size_t OFF_Y1   = 0x840000;
static constexpr size_t OFF_Y2   = 0x880000;
static constexpr size_t OFF_Y3   = 0x8C0000;
static constexpr size_t OFF_CQ   = 0x900000;  // f32 [64][1024]
static constexpr size_t OFF_S64  = 0x940000;  // f64 [64*64] gram
static constexpr size_t OFF_LF   = 0x948000;  // f32 [64*64] chol factor (recip diag)
static constexpr size_t OFF_T64  = 0x950000;  // f64 [64*64] RR matrix
static constexpr size_t OFF_V64  = 0x958000;  // f32 [64*64] eigvecs
static constexpr size_t OFF_EIG  = 0x95C000;  // f32 [64]
static constexpr size_t OFF_IDX  = 0x95C100;  // int [16]
static constexpr size_t OFF_UT   = 0x960000;  // f32 [16][1024]
static constexpr size_t OFF_UTT  = 0x970000;  // f32 [1024][16]
static constexpr size_t OFF_S16  = 0x980000;  // f32 [16]
static constexpr size_t OFF_CS   = 0x980100;  // f32 [1024] colsum           [ZERO]
static constexpr size_t OFF_TR   = 0x981100;  // f32 [1] trace               [ZERO]
static constexpr size_t OFF_SCAL = 0x981200;  // f32 [2] mid, inv_e
static constexpr size_t OFF_STAT = 0x981300;  // f32 [10*153] stats          [ZERO]
static constexpr size_t OFF_F    = 0x990000;  // f32 [16384*16] features
// end ~0xA90000 (~11.1 MB of ws used)

// ---------------- kernels ----------------

// column sums of X (64 blocks x 256 thr; thread owns 4 columns)
__global__ __launch_bounds__(256) void colsum_k(const float* __restrict__ X, float* __restrict__ cs){
  int b = blockIdx.x, t = threadIdx.x;
  float a0=0.f,a1=0.f,a2=0.f,a3=0.f;
  for (int r=0; r<256; ++r){
    const float4 v = *(const float4*)(X + (size_t)(b*256 + r)*1024 + t*4);
    a0 += v.x; a1 += v.y; a2 += v.z; a3 += v.w;
  }
  atomicAdd(&cs[t*4+0], a0); atomicAdd(&cs[t*4+1], a1);
  atomicAdd(&cs[t*4+2], a2); atomicAdd(&cs[t*4+3], a3);
}

// G = X^T X, upper 128x128 tiles only, split-K=14, atomicAdd accumulate.
__global__ __launch_bounds__(256) void syrk_k(const float* __restrict__ X, float* __restrict__ G){
  int bx = blockIdx.x;
  int tp = bx % 36, ks = bx / 36;
  int ti = 0, rem = tp;
  while (rem >= 8 - ti){ rem -= 8 - ti; ++ti; }
  int tj = ti + rem;                      // ti <= tj
  int k0 = ks * 1184;
  int kend = k0 + 1184; if (kend > 16384) kend = 16384;
  __shared__ __attribute__((aligned(16))) float Xa[16][132];
  __shared__ __attribute__((aligned(16))) float Xb[16][132];
  int t = threadIdx.x;
  int tx = t & 15, ty = t >> 4;
  float acc[8][8];
  #pragma unroll
  for (int i=0;i<8;++i)
    #pragma unroll
    for (int j=0;j<8;++j) acc[i][j] = 0.f;
  for (int kc = k0; kc < kend; kc += 16){
    __syncthreads();
    #pragma unroll
    for (int w=0; w<2; ++w){
      int job = t + 256*w;
      int kk = job >> 5, f4i = job & 31;
      *(float4*)&Xa[kk][f4i*4] = *(const float4*)(X + (size_t)(kc+kk)*1024 + ti*128 + f4i*4);
      *(float4*)&Xb[kk][f4i*4] = *(const float4*)(X + (size_t)(kc+kk)*1024 + tj*128 + f4i*4);
    }
    __syncthreads();
    #pragma unroll
    for (int kk=0; kk<16; ++kk){
      float a[8], b[8];
      *(float4*)&a[0] = *(const float4*)&Xa[kk][tx*8];
      *(float4*)&a[4] = *(const float4*)&Xa[kk][tx*8+4];
      *(float4*)&b[0] = *(const float4*)&Xb[kk][ty*8];
      *(float4*)&b[4] = *(const float4*)&Xb[kk][ty*8+4];
      #pragma unroll
      for (int i=0;i<8;++i)
        #pragma unroll
        for (int j=0;j<8;++j) acc[i][j] += a[i]*b[j];
    }
  }
  #pragma unroll
  for (int i=0;i<8;++i)
    #pragma unroll
    for (int j=0;j<8;++j)
      atomicAdd(&G[(size_t)(ti*128 + tx*8 + i)*1024 + tj*128 + ty*8 + j], acc[i][j]);
}

// C = G - cs_i cs_j / B, mirror to lower, accumulate trace
__global__ __launch_bounds__(256) void formC_k(float* __restrict__ C, const float* __restrict__ cs, float* __restrict__ tr){
  int g = blockIdx.x*256 + threadIdx.x;
  int i = g >> 10, j = g & 1023;
  if (j < i) return;
  float v = C[g] - cs[i]*cs[j]*(1.0f/16384.0f);
  C[g] = v;
  C[j*1024 + i] = v;
  if (i == j) atomicAdd(tr, v);
}

// Chebyshev interval params from trace: [0.25, 1.40]*(tr/D)
__global__ void scal_k(const float* __restrict__ tr, float* __restrict__ scal){
  float trD = tr[0] * (1.0f/1024.0f);
  float c = 1.40f * trD, a = 0.25f * trD;
  scal[0] = 0.5f*(c + a);       // mid
  scal[1] = 2.0f/(c - a);       // 1/e
}

// deterministic random init for Omega (Y layout: [64 cols][1024], row-major)
__global__ void rng_k(float* __restrict__ Y){
  int idx = blockIdx.x*256 + threadIdx.x;   // 65536
  unsigned h = (unsigned)idx * 2654435761u;
  h ^= h >> 16; h *= 2246822519u; h ^= h >> 13; h *= 3266489917u; h ^= h >> 16;
  Y[idx] = (float)(h & 0xFFFFFFu) * (2.0f/16777216.0f) - 1.0f;
}

// partial[ks] = Yt * C  for k-chunk ks (M=64, N=64 tile, K=64 chunk). grid 256.
__global__ __launch_bounds__(256) void mv_k(const float* __restrict__ Yt, const float* __restrict__ Cm, float* __restrict__ P){
  int bx = blockIdx.x;
  int nt = bx & 15, ks = bx >> 4;
  int n0 = nt*64, k0 = ks*64;
  __shared__ __attribute__((aligned(16))) float At[64][68];
  __shared__ __attribute__((aligned(16))) float Bt[64][68];
  int t = threadIdx.x;
  #pragma unroll
  for (int w=0; w<4; ++w){
    int job = t + 256*w;
    int m  = job >> 4, f4 = job & 15;
    float4 v = *(const float4*)(Yt + (size_t)m*1024 + k0 + f4*4);
    At[f4*4+0][m] = v.x; At[f4*4+1][m] = v.y; At[f4*4+2][m] = v.z; At[f4*4+3][m] = v.w;
    int kk = job >> 4, fn = job & 15;
    *(float4*)&Bt[kk][fn*4] = *(const float4*)(Cm + (size_t)(k0+kk)*1024 + n0 + fn*4);
  }
  __syncthreads();
  int tm = t & 15, tn = t >> 4;
  float acc[4][4];
  #pragma unroll
  for (int i=0;i<4;++i)
    #pragma unroll
    for (int j=0;j<4;++j) acc[i][j]=0.f;
  for (int kk=0; kk<64; ++kk){
    float4 a = *(const float4*)&At[kk][tm*4];
    float4 b = *(const float4*)&Bt[kk][tn*4];
    float av[4] = {a.x,a.y,a.z,a.w};
    float bv[4] = {b.x,b.y,b.z,b.w};
    #pragma unroll
    for (int i=0;i<4;++i)
      #pragma unroll
      for (int j=0;j<4;++j) acc[i][j] += av[i]*bv[j];
  }
  #pragma unroll
  for (int i=0;i<4;++i){
    float4 o; o.x=acc[i][0]; o.y=acc[i][1]; o.z=acc[i][2]; o.w=acc[i][3];
    *(float4*)(P + (size_t)(ks*64 + tm*4 + i)*1024 + n0 + tn*4) = o;
  }
}

// combine 16 partials + Chebyshev AXPY. mode 0: T1 = ie*(S - mid*T0); mode 1: 2ie*(S - mid*Tk) - Tk1; mode 2: plain S
__global__ __launch_bounds__(256) void combine_k(const float* __restrict__ P, const float* __restrict__ Tk,
                                                 const float* __restrict__ Tk1, float* __restrict__ out,
                                                 const float* __restrict__ scal, int mode){
  int idx = (blockIdx.x*256 + threadIdx.x)*4;
  float s0=0.f,s1=0.f,s2=0.f,s3=0.f;
  #pragma unroll
  for (int ks=0; ks<16; ++ks){
    const float4 p = *(const float4*)(P + (size_t)ks*65536 + idx);
    s0 += p.x; s1 += p.y; s2 += p.z; s3 += p.w;
  }
  float4 o;
  if (mode == 2){ o.x=s0;o.y=s1;o.z=s2;o.w=s3; *(float4*)(out+idx)=o; return; }
  float mid = scal[0], ie = scal[1];
  const float4 tk = *(const float4*)(Tk + idx);
  if (mode == 0){
    o.x = ie*(s0 - mid*tk.x); o.y = ie*(s1 - mid*tk.y);
    o.z = ie*(s2 - mid*tk.z); o.w = ie*(s3 - mid*tk.w);
  } else {
    const float4 t1 = *(const float4*)(Tk1 + idx);
    float ie2 = 2.f*ie;
    o.x = ie2*(s0 - mid*tk.x) - t1.x; o.y = ie2*(s1 - mid*tk.y) - t1.y;
    o.z = ie2*(s2 - mid*tk.z) - t1.z; o.w = ie2*(s3 - mid*tk.w) - t1.w;
  }
  *(float4*)(out+idx) = o;
}

// S[i][j] = sum_k A[i][k]*B[j][k]  (fp64 accumulate). grid 256: i = bx>>2, jg = bx&3.
__global__ __launch_bounds__(256) void gram_k(const float* __restrict__ A, const float* __restrict__ Bm, double* __restrict__ S){
  int bx = blockIdx.x;
  int i = bx >> 2, jg = bx & 3;
  __shared__ __attribute__((aligned(16))) float Ai[1024];
  __shared__ double red[16][17];
  int t = threadIdx.x;
  ((float4*)Ai)[t] = ((const float4*)(A + (size_t)i*1024))[t];
  __syncthreads();
  int jl = t >> 4, kp = t & 15;
  const float* Br = Bm + (size_t)(jg*16 + jl)*1024 + kp*64;
  const float* Ar = Ai + kp*64;
  double acc = 0.0;
  #pragma unroll 8
  for (int kk=0; kk<64; ++kk) acc += (double)Br[kk] * (double)Ar[kk];
  red[jl][kp] = acc;
  __syncthreads();
  if (t < 16){
    double s = 0.0;
    #pragma unroll
    for (int p2=0; p2<16; ++p2) s += red[t][p2];
    S[i*64 + jg*16 + t] = s;
  }
}

// fp64 Cholesky of 64x64 S; outputs fp32 lower factor with RECIPROCAL diagonal.
__global__ __launch_bounds__(256) void chol_k(const double* __restrict__ S, float* __restrict__ Lf){
  __shared__ double L[64][65];
  int t = threadIdx.x;
  for (int e=t; e<4096; e+=256) L[e>>6][e&63] = S[e];
  __syncthreads();
  for (int k=0; k<64; ++k){
    if (t == 0) L[k][k] = sqrt(fmax(L[k][k], 1e-280));
    __syncthreads();
    if (t > k && t < 64) L[t][k] /= L[k][k];
    __syncthreads();
    int i = t & 63, js = t >> 6;
    for (int j = k+1+js; j <= i; j += 4) L[i][j] -= L[i][k]*L[j][k];
    __syncthreads();
  }
  for (int e=t; e<4096; e+=256){
    int i = e >> 6, j = e & 63;
    Lf[e] = (j < i) ? (float)L[i][j] : ((j == i) ? (float)(1.0/L[i][i]) : 0.f);
  }
}

// Qt = L^{-1} Yt by forward substitution per column k (1024 threads over 4 blocks)
__global__ __launch_bounds__(256) void applysolve_k(const float* __restrict__ Yin, const float* __restrict__ Lf, float* __restrict__ Qout){
  int k = blockIdx.x*256 + threadIdx.x;
  float z[64];
  #pragma unroll
  for (int c=0; c<64; ++c){
    float v = Yin[(size_t)c*1024 + k];
    #pragma unroll
    for (int j=0; j<c; ++j) v -= Lf[c*64+j]*z[j];
    z[c] = v * Lf[c*64+c];   // diag stores reciprocal
  }
  #pragma unroll
  for (int c=0; c<64; ++c) Qout[(size_t)c*1024 + k] = z[c];
}

__device__ __forceinline__ int ins0(int x, int h){ return ((x >> h) << (h+1)) | (x & ((1<<h)-1)); }

// 64x64 symmetric eigensolve: parallel Jacobi with XOR pairing, 6 sweeps, fp32, one WG.
__global__ __launch_bounds__(256) void jacobi_k(const double* __restrict__ Tin, float* __restrict__ Vout, float* __restrict__ eig){
  __shared__ float A[64][65];
  __shared__ float V[64][65];
  __shared__ float ca[64], sa[64];
  int t = threadIdx.x;
  for (int e=t; e<4096; e+=256){
    int i = e >> 6, j = e & 63;
    A[i][j] = (float)(0.5*(Tin[i*64+j] + Tin[j*64+i]));
    V[i][j] = (i == j) ? 1.f : 0.f;
  }
  __syncthreads();
  for (int sw=0; sw<6; ++sw){
    for (int m=1; m<64; ++m){
      int h = 31 - __builtin_clz(m);
      if (t < 32){
        int p = ins0(t, h), q = p ^ m;
        float app = A[p][p], aqq = A[q][q], apq = A[p][q];
        float c = 1.f, s = 0.f;
        if (fabsf(apq) > (fabsf(app)+fabsf(aqq))*1e-12f + 1e-28f){
          float tau = (aqq - app)/(2.f*apq);
          float tt = 1.f/(fabsf(tau) + sqrtf(1.f + tau*tau));
          if (tau < 0.f) tt = -tt;
          float cc = 1.f/sqrtf(1.f + tt*tt);
          c = cc; s = tt*cc;
        }
        ca[p] = c; sa[p] = -s;
        ca[q] = c; sa[q] =  s;
      }
      __syncthreads();
      // A: 32 rowpairs x 32 colpairs, one-shot quad update (4 reads -> 4 outputs)
      int rp = t & 31, cp0 = (t >> 5) << 2;
      int p = ins0(rp, h), q = p ^ m;
      float cr = ca[p], sp = sa[p], sq = sa[q];
      float na[16];
      #pragma unroll
      for (int cc=0; cc<4; ++cc){
        int jl = ins0(cp0+cc, h), jh = jl ^ m;
        float cj = ca[jl], sl = sa[jl], sh2 = sa[jh];
        float av = A[p][jl], bv = A[p][jh], cv = A[q][jl], dv = A[q][jh];
        float x1 = cj*av + sl*bv;
        float x2 = cj*bv + sh2*av;
        float y1 = cj*cv + sl*dv;
        float y2 = cj*dv + sh2*cv;
        na[cc*4+0] = cr*x1 + sp*y1;
        na[cc*4+1] = cr*x2 + sp*y2;
        na[cc*4+2] = cr*y1 + sq*x1;
        na[cc*4+3] = cr*y2 + sq*x2;
      }
      // V: column rotations only
      int r = t & 63, vp0 = (t >> 6) << 3;
      float nv[16];
      #pragma unroll
      for (int cc=0; cc<8; ++cc){
        int jl = ins0(vp0+cc, h), jh = jl ^ m;
        float cj = ca[jl], sl = sa[jl], sh2 = sa[jh];
        float a0 = V[r][jl], b0 = V[r][jh];
        nv[cc*2+0] = cj*a0 + sl*b0;
        nv[cc*2+1] = cj*b0 + sh2*a0;
      }
      __syncthreads();
      #pragma unroll
      for (int cc=0; cc<4; ++cc){
        int jl = ins0(cp0+cc, h), jh = jl ^ m;
        A[p][jl] = na[cc*4+0]; A[p][jh] = na[cc*4+1];
        A[q][jl] = na[cc*4+2]; A[q][jh] = na[cc*4+3];
      }
      #pragma unroll
      for (int cc=0; cc<8; ++cc){
        int jl = ins0(vp0+cc, h), jh = jl ^ m;
        V[r][jl] = nv[cc*2+0]; V[r][jh] = nv[cc*2+1];
      }
      __syncthreads();
    }
  }
  for (int e=t; e<4096; e+=256) Vout[e] = V[e>>6][e&63];
  if (t < 64) eig[t] = A[t][t];
}

__global__ void select_k(const float* __restrict__ eig, int* __restrict__ IDX){
  __shared__ float ev[64];
  int t = threadIdx.x;
  if (t < 64) ev[t] = eig[t];
  __syncthreads();
  if (t == 0){
    for (int m=0; m<16; ++m){
      int bi = 0; float bv = -3e38f;
      for (int j=0; j<64; ++j) if (ev[j] > bv){ bv = ev[j]; bi = j; }
      IDX[m] = bi; ev[bi] = -3e38f;
    }
  }
}

// Ut[c][k] = sum_j V[j][idx_c] * Qt[j][k]; also transposed copy UtT[k][c]
__global__ __launch_bounds__(256) void buildUt_k(const float* __restrict__ V64, const int* __restrict__ IDX,
                                                 const float* __restrict__ Qt, float* __restrict__ Ut, float* __restrict__ UtT){
  int bx = blockIdx.x;
  int c = bx & 15, kc = bx >> 4;
  int k = kc*256 + threadIdx.x;
  int ic = IDX[c];
  float acc = 0.f;
  #pragma unroll
  for (int j=0; j<64; ++j) acc += V64[j*64 + ic] * Qt[(size_t)j*1024 + k];
  Ut[(size_t)c*1024 + k] = acc;
  UtT[(size_t)k*16 + c] = acc;
}

// s16[c] = (colsum . U[:,c]) / B
__global__ void s16_k(const float* __restrict__ cs, const float* __restrict__ Ut, float* __restrict__ s16){
  __shared__ float red[16][17];
  int t = threadIdx.x;
  int c = t & 15, part = t >> 4;
  float acc = 0.f;
  for (int d=0; d<64; ++d) acc += cs[part*64 + d] * Ut[(size_t)c*1024 + part*64 + d];
  red[c][part] = acc;
  __syncthreads();
  if (t < 16){
    float s = 0.f;
    #pragma unroll
    for (int p2=0; p2<16; ++p2) s += red[t][p2];
    s16[t] = s * (1.0f/16384.0f);
  }
}

// F[b][c] = sum_d X[b][d]*U[d][c] - s16[c]. grid 256 blocks x 64 rows.
__global__ __launch_bounds__(256) void proj_k(const float* __restrict__ X, const float* __restrict__ UtT,
                                              const float* __restrict__ s16, float* __restrict__ F){
  int r0 = blockIdx.x * 64;
  int t = threadIdx.x;
  int row = t & 63, kp = t >> 6;
  const float* xr = X + (size_t)(r0 + row)*1024 + kp*256;
  const float* ut = UtT + (size_t)kp*256*16;
  float acc[16];
  #pragma unroll
  for (int c=0;c<16;++c) acc[c] = 0.f;
  for (int dd=0; dd<256; ++dd){
    float xv = xr[dd];
    #pragma unroll
    for (int c=0;c<16;++c) acc[c] += xv * ut[dd*16 + c];
  }
  __shared__ float part[4][64][16];
  #pragma unroll
  for (int c=0;c<16;++c) part[kp][row][c] = acc[c];
  __syncthreads();
  int cq = t >> 6;
  #pragma unroll
  for (int cc=0; cc<4; ++cc){
    int c = cq*4 + cc;
    float v = part[0][row][c] + part[1][row][c] + part[2][row][c] + part[3][row][c] - s16[c];
    F[(size_t)(r0 + row)*16 + c] = v;
  }
}

// per-class count / sum / second-moment (upper triangle) stats
__global__ __launch_bounds__(256) void stats_k(const float* __restrict__ F, const int* __restrict__ lbl, float* __restrict__ SG){
  __shared__ float st[10][154];
  int t = threadIdx.x;
  for (int e=t; e<1540; e+=256) st[e/154][e%154] = 0.f;
  __syncthreads();
  int r = blockIdx.x*256 + t;
  float f[16];
  #pragma unroll
  for (int w=0; w<4; ++w){
    float4 v = *(const float4*)(F + (size_t)r*16 + w*4);
    f[w*4+0]=v.x; f[w*4+1]=v.y; f[w*4+2]=v.z; f[w*4+3]=v.w;
  }
  int c = lbl[r];
  if ((unsigned)c < 10u){
    float* bs = &st[c][0];
    atomicAdd(&bs[0], 1.f);
    #pragma unroll
    for (int a=0;a<16;++a) atomicAdd(&bs[1+a], f[a]);
    int sidx = 17;
    #pragma unroll
    for (int a=0;a<16;++a)
      #pragma unroll
      for (int b2=a;b2<16;++b2) atomicAdd(&bs[sidx++], f[a]*f[b2]);
  }
  __syncthreads();
  for (int e=t; e<1530; e+=256) atomicAdd(&SG[e], st[e/153][e%153]);
}

// final: means, Sigma, fp64 Cholesky inverse + logdet, pairwise KL, weighted sum / B^3
__global__ __launch_bounds__(256) void final_k(const float* __restrict__ SG, float* __restrict__ out){
  __shared__ double cnt[10], safe[10], ldet[10];
  __shared__ double mean[10][16];
  __shared__ double Sig[10][16][16];
  __shared__ double Inv[10][16][16];
  __shared__ double red[128];
  int t = threadIdx.x;
  if (t < 10){
    double c0 = (double)SG[t*153];
    cnt[t] = c0; safe[t] = (c0 > 0.0) ? c0 : 1.0;
  }
  __syncthreads();
  for (int e=t; e<160; e+=256){
    int c = e >> 4, a = e & 15;
    mean[c][a] = (double)SG[c*153 + 1 + a] / safe[c];
  }
  __syncthreads();
  for (int e=t; e<2560; e+=256){
    int c = e >> 8, ab = e & 255, a = ab >> 4, b2 = ab & 15;
    int lo = a < b2 ? a : b2, hi = a < b2 ? b2 : a;
    int ti = lo*(33 - lo)/2 + (hi - lo);
    Sig[c][a][b2] = (double)SG[c*153 + 17 + ti]/safe[c] - mean[c][a]*mean[c][b2] + ((a==b2)?1.0:0.0);
  }
  __syncthreads();
  if (t < 10){
    for (int a=0;a<16;++a)
      for (int b2=0;b2<16;++b2) Inv[t][a][b2] = Sig[t][a][b2];
    double ld2 = 0.0;
    for (int k=0;k<16;++k){
      double v = Inv[t][k][k];
      for (int j=0;j<k;++j) v -= Inv[t][k][j]*Inv[t][k][j];
      v = fmax(v, 1e-280);
      double lkk = sqrt(v);
      Inv[t][k][k] = lkk; ld2 += log(lkk);
      for (int i=k+1;i<16;++i){
        double w = Inv[t][i][k];
        for (int j=0;j<k;++j) w -= Inv[t][i][j]*Inv[t][k][j];
        Inv[t][i][k] = w / lkk;
      }
    }
    ldet[t] = 2.0*ld2;
    // invert lower triangle in place
    for (int j=0;j<16;++j){
      double dj = 1.0 / Inv[t][j][j];
      Inv[t][j][j] = dj;
      for (int i=j+1;i<16;++i){
        double ssum = Inv[t][i][j]*dj;
        for (int k=j+1;k<i;++k) ssum += Inv[t][i][k]*Inv[t][k][j];
        Inv[t][i][j] = -ssum / Inv[t][i][i];
      }
    }
    // Inv = Li^T Li  (upper first, then diag, then mirror)
    double dg[16];
    #pragma unroll
    for (int a=0;a<16;++a){
      double s2 = 0.0;
      for (int k=a;k<16;++k){ double x = Inv[t][k][a]; s2 += x*x; }
      dg[a] = s2;
    }
    for (int a=0;a<16;++a)
      for (int b2=a+1;b2<16;++b2){
        double s2 = 0.0;
        for (int k=b2;k<16;++k) s2 += Inv[t][k][a]*Inv[t][k][b2];
        Inv[t][a][b2] = s2;
      }
    for (int a=0;a<16;++a) Inv[t][a][a] = dg[a];
    for (int a=0;a<16;++a)
      for (int b2=a+1;b2<16;++b2) Inv[t][b2][a] = Inv[t][a][b2];
  }
  __syncthreads();
  double contrib = 0.0;
  if (t < 100){
    int i = t/10, j = t%10;
    if (i != j && cnt[i] > 0.0 && cnt[j] > 0.0){
      double tr = 0.0;
      for (int a=0;a<16;++a)
        for (int b2=0;b2<16;++b2) tr += Inv[j][a][b2]*Sig[i][b2][a];
      double dm[16];
      #pragma unroll
      for (int a=0;a<16;++a) dm[a] = mean[j][a] - mean[i][a];
      double mah = 0.0;
      for (int a=0;a<16;++a){
        double rs = 0.0;
        for (int b2=0;b2<16;++b2) rs += Inv[j][a][b2]*dm[b2];
        mah += dm[a]*rs;
      }
      double kl = 0.5*(tr + mah - 16.0 + ldet[j] - ldet[i]);
      contrib = kl * cnt[i]*cnt[j];
    }
  }
  if (t < 128) red[t] = contrib;
  __syncthreads();
  for (int off=64; off>0; off >>= 1){
    if (t < off) red[t] += red[t+off];
    __syncthreads();
  }
  if (t == 0) out[0] = (float)(red[0] / (16384.0*16384.0*16384.0));
}

// ---------------- host ----------------
extern "C" void kernel_launch(void* const* d_in, const int* in_sizes, int n_in,
                              void* d_out, int out_size, void* d_ws, size_t ws_size,
                              hipStream_t stream){
  (void)in_sizes; (void)n_in; (void)out_size; (void)ws_size;
  const float* X  = (const float*)d_in[0];
  const int* lbl  = (const int*)d_in[1];
  char* ws = (char*)d_ws;
  float*  C    = (float*)(ws + OFF_C);
  float*  P    = (float*)(ws + OFF_P);
  float*  Y0   = (float*)(ws + OFF_Y0);
  float*  Y1   = (float*)(ws + OFF_Y1);
  float*  Y2   = (float*)(ws + OFF_Y2);
  float*  Y3   = (float*)(ws + OFF_Y3);
  float*  CQ   = (float*)(ws + OFF_CQ);
  double* S64  = (double*)(ws + OFF_S64);
  float*  LF   = (float*)(ws + OFF_LF);
  double* T64  = (double*)(ws + OFF_T64);
  float*  V64  = (float*)(ws + OFF_V64);
  float*  EIG  = (float*)(ws + OFF_EIG);
  int*    IDX  = (int*)(ws + OFF_IDX);
  float*  UT   = (float*)(ws + OFF_UT);
  float*  UTT  = (float*)(ws + OFF_UTT);
  float*  S16  = (float*)(ws + OFF_S16);
  float*  CS   = (float*)(ws + OFF_CS);
  float*  TRC  = (float*)(ws + OFF_TR);
  float*  SCAL = (float*)(ws + OFF_SCAL);
  float*  STAT = (float*)(ws + OFF_STAT);
  float*  F    = (float*)(ws + OFF_F);
  float*  OUT  = (float*)d_out;

  // zero accumulators (ws is poisoned before every call)
  hipMemsetAsync(C, 0, 4*1024*1024, stream);
  hipMemsetAsync(ws + OFF_CS, 0, 12800, stream);   // CS + TR + SCAL + STAT

  colsum_k<<<64, 256, 0, stream>>>(X, CS);
  syrk_k<<<504, 256, 0, stream>>>(X, C);
  formC_k<<<4096, 256, 0, stream>>>(C, CS, TRC);
  scal_k<<<1, 1, 0, stream>>>(TRC, SCAL);
  rng_k<<<256, 256, 0, stream>>>(Y0);

  // Chebyshev stage: degree CHEB_D, 3 rotating scratch buffers
  auto cheb = [&](float* in, float* z0, float* z1, float* z2) -> float* {
    float* bufs[3] = {z0, z1, z2};
    float* prev = in;
    float* cur = in;
    for (int s=0; s<CHEB_D; ++s){
      float* src = cur;
      float* dst = bufs[s % 3];
      mv_k<<<256, 256, 0, stream>>>(src, C, P);
      combine_k<<<64, 256, 0, stream>>>(P, src, prev, dst, SCAL, (s == 0) ? 0 : 1);
      prev = src; cur = dst;
    }
    return cur;
  };
  auto cholqr = [&](float* Yin, float* Qout){
    gram_k<<<256, 256, 0, stream>>>(Yin, Yin, S64);
    chol_k<<<1, 256, 0, stream>>>(S64, LF);
    applysolve_k<<<4, 256, 0, stream>>>(Yin, LF, Qout);
  };

  // stage 1: filter random block, CholQR2
  float* t20 = cheb(Y0, Y1, Y2, Y3);   // -> Y2
  cholqr(t20, Y3);
  cholqr(Y3, Y1);                      // Q1 = Y1
  // stage 2
  float* t20b = cheb(Y1, Y0, Y2, Y3);  // -> Y2
  cholqr(t20b, Y3);
  cholqr(Y3, Y0);                      // Qf = Y0

  // Rayleigh-Ritz: T = Q^T C Q
  mv_k<<<256, 256, 0, stream>>>(Y0, C, P);
  combine_k<<<64, 256, 0, stream>>>(P, Y0, Y0, CQ, SCAL, 2);   // plain: CQ = Q^T C
  gram_k<<<256, 256, 0, stream>>>(Y0, CQ, T64);
  jacobi_k<<<1, 256, 0, stream>>>(T64, V64, EIG);
  select_k<<<1, 64, 0, stream>>>(EIG, IDX);
  buildUt_k<<<64, 256, 0, stream>>>(V64, IDX, Y0, UT, UTT);

  // project and GMM loss
  s16_k<<<1, 256, 0, stream>>>(CS, UT, S16);
  proj_k<<<256, 256, 0, stream>>>(X, UTT, S16, F);
  stats_k<<<64, 256, 0, stream>>>(F, lbl, STAT);
  final_k<<<1, 256, 0, stream>>>(STAT, OUT);
}